// Round 1
// baseline (711.924 us; speedup 1.0000x reference)
//
#include <hip/hip_runtime.h>
#include <cstdint>
#include <cstddef>

#ifndef __has_builtin
#define __has_builtin(x) 0
#endif

constexpr int OSC  = 2048;
constexpr int MHID = 4096;

// Shifted-copy stride: each cat vector is stored 4 times, copy s shifted left
// by s floats (copy_s[t] = cat[s+t]), each copy 16B-aligned. This lets the
// ih-row dot run float4-vs-float4 regardless of the odd (L%4==1) row offsets.
constexpr int SH = 4112;  // >= 4101, multiple of 4

constexpr int WS_M_SH   = 0;                  // m cat: [5 obs][h1_s][h2_s] len 4101
constexpr int WS_K1_SH  = WS_M_SH  + 4 * SH;  // [x3][h1_s][f1_s] len 4097
constexpr int WS_K2_SH  = WS_K1_SH + 4 * SH;  // [x6][h2_s][f2_s] len 4097
constexpr int WS_F1_SH  = WS_K2_SH + 4 * SH;  // [x4][f1_s] len 2049
constexpr int WS_F2_SH  = WS_F1_SH + 4 * SH;  // [x7][f2_s] len 2049
constexpr int WS_H1_SH  = WS_F2_SH + 4 * SH;  // [x2][out_m lo][k1_s] len 4097
constexpr int WS_H2_SH  = WS_H1_SH + 4 * SH;  // [x5][out_m hi][k2_s] len 4097
constexpr int WS_M_NEW  = WS_H2_SH + 4 * SH;  // 4096
constexpr int WS_H1_NEW = WS_M_NEW + MHID;
constexpr int WS_H2_NEW = WS_H1_NEW + OSC;
constexpr int WS_K1_NEW = WS_H2_NEW + OSC;
constexpr int WS_K2_NEW = WS_K1_NEW + OSC;
constexpr int WS_F1_NEW = WS_K2_NEW + OSC;
constexpr int WS_F2_NEW = WS_F1_NEW + OSC;    // end ~131.5k floats = 526 KB

typedef float f4 __attribute__((ext_vector_type(4)));

// Weights are read exactly once per call: nontemporal keeps them from
// evicting the hot x-vectors / shifted cats out of L2.
__device__ __forceinline__ f4 ldw(const f4* p) {
#if __has_builtin(__builtin_nontemporal_load)
  return __builtin_nontemporal_load(p);
#else
  return *p;
#endif
}

__device__ __forceinline__ float dot4(f4 a, f4 b) {
  return a.x * b.x + a.y * b.y + a.z * b.z + a.w * b.w;
}

__device__ __forceinline__ float wave_sum(float v) {
#pragma unroll
  for (int s = 32; s > 0; s >>= 1) v += __shfl_down(v, s, 64);
  return v;
}

__device__ __forceinline__ void wsum3(float& a, float& b, float& c) {
#pragma unroll
  for (int s = 32; s > 0; s >>= 1) {
    a += __shfl_down(a, s, 64);
    b += __shfl_down(b, s, 64);
    c += __shfl_down(c, s, 64);
  }
}

__device__ __forceinline__ void wsum4(float& a, float& b, float& c, float& d) {
#pragma unroll
  for (int s = 32; s > 0; s >>= 1) {
    a += __shfl_down(a, s, 64);
    b += __shfl_down(b, s, 64);
    c += __shfl_down(c, s, 64);
    d += __shfl_down(d, s, 64);
  }
}

__device__ __forceinline__ void wsum6(float& a, float& b, float& c,
                                      float& d, float& e, float& f) {
#pragma unroll
  for (int s = 32; s > 0; s >>= 1) {
    a += __shfl_down(a, s, 64);
    b += __shfl_down(b, s, 64);
    c += __shfl_down(c, s, 64);
    d += __shfl_down(d, s, 64);
    e += __shfl_down(e, s, 64);
    f += __shfl_down(f, s, 64);
  }
}

__device__ __forceinline__ float sigf(float x) { return 1.0f / (1.0f + expf(-x)); }

// Write value v at cat index idx into all 4 shifted copies.
__device__ __forceinline__ void put4(float* __restrict__ ws, int base, int idx, float v) {
#pragma unroll
  for (int s = 0; s < 4; ++s)
    if (idx >= s) ws[base + s * SH + idx - s] = v;
}

// ---------- fused 3-gate dots -----------------------------------------------
// All three gate rows share the same 4B misalignment (gate stride * RL ≡ 0 mod 4),
// so one peel + one shifted x copy serves all three streams.

// ih (unaligned rows, shifted-copy x), single x vector. Partial sums (unreduced).
__device__ __forceinline__ void dot3_ih(const float* __restrict__ w0r,
                                        const float* __restrict__ w1r,
                                        const float* __restrict__ w2r,
                                        int L, const float* __restrict__ ws, int cat,
                                        float& r0, float& r1, float& r2) {
  const int lane = threadIdx.x & 63;
  const int mis = ((int)((uintptr_t)w0r >> 2)) & 3;
  const int p = (4 - mis) & 3;
  const float* __restrict__ x0 = ws + cat;
  float a0 = 0.f, a1 = 0.f, a2 = 0.f, b0 = 0.f, b1 = 0.f, b2 = 0.f;
  if (lane < p) {
    float xv = x0[lane];
    a0 = w0r[lane] * xv; a1 = w1r[lane] * xv; a2 = w2r[lane] * xv;
  }
  const int n4 = (L - p) >> 2;
  const f4* __restrict__ w04 = (const f4*)(w0r + p);
  const f4* __restrict__ w14 = (const f4*)(w1r + p);
  const f4* __restrict__ w24 = (const f4*)(w2r + p);
  const f4* __restrict__ x4  = (const f4*)(ws + cat + p * SH);
  int i = lane;
  for (; i + 64 < n4; i += 128) {
    f4 xa = x4[i], xb = x4[i + 64];
    f4 u0 = ldw(w04 + i),      u1 = ldw(w14 + i),      u2 = ldw(w24 + i);
    f4 v0 = ldw(w04 + i + 64), v1 = ldw(w14 + i + 64), v2 = ldw(w24 + i + 64);
    a0 += dot4(u0, xa); a1 += dot4(u1, xa); a2 += dot4(u2, xa);
    b0 += dot4(v0, xb); b1 += dot4(v1, xb); b2 += dot4(v2, xb);
  }
  for (; i < n4; i += 64) {
    f4 xa = x4[i];
    a0 += dot4(ldw(w04 + i), xa);
    a1 += dot4(ldw(w14 + i), xa);
    a2 += dot4(ldw(w24 + i), xa);
  }
  for (int t = p + (n4 << 2) + lane; t < L; t += 64) {
    float xv = x0[t];
    a0 += w0r[t] * xv; a1 += w1r[t] * xv; a2 += w2r[t] * xv;
  }
  r0 = a0 + b0; r1 = a1 + b1; r2 = a2 + b2;
}

// ih dual-x (shared weight rows vs two cat vectors). 6 partial sums.
__device__ __forceinline__ void dot3_ih2(const float* __restrict__ w0r,
                                         const float* __restrict__ w1r,
                                         const float* __restrict__ w2r,
                                         int L, const float* __restrict__ ws,
                                         int cata, int catb,
                                         float& r0, float& r1, float& r2,
                                         float& r3, float& r4, float& r5) {
  const int lane = threadIdx.x & 63;
  const int mis = ((int)((uintptr_t)w0r >> 2)) & 3;
  const int p = (4 - mis) & 3;
  const float* __restrict__ xa0 = ws + cata;
  const float* __restrict__ xb0 = ws + catb;
  float s0 = 0.f, s1 = 0.f, s2 = 0.f, s3 = 0.f, s4 = 0.f, s5 = 0.f;
  float t0 = 0.f, t1 = 0.f, t2 = 0.f, t3 = 0.f, t4 = 0.f, t5 = 0.f;
  if (lane < p) {
    float w0 = w0r[lane], w1 = w1r[lane], w2 = w2r[lane];
    float av = xa0[lane], bv = xb0[lane];
    s0 = w0 * av; s1 = w1 * av; s2 = w2 * av;
    s3 = w0 * bv; s4 = w1 * bv; s5 = w2 * bv;
  }
  const int n4 = (L - p) >> 2;
  const f4* __restrict__ w04 = (const f4*)(w0r + p);
  const f4* __restrict__ w14 = (const f4*)(w1r + p);
  const f4* __restrict__ w24 = (const f4*)(w2r + p);
  const f4* __restrict__ a4  = (const f4*)(ws + cata + p * SH);
  const f4* __restrict__ b4  = (const f4*)(ws + catb + p * SH);
  int i = lane;
  for (; i + 64 < n4; i += 128) {
    f4 av = a4[i], bv = b4[i], av2 = a4[i + 64], bv2 = b4[i + 64];
    f4 u0 = ldw(w04 + i),      u1 = ldw(w14 + i),      u2 = ldw(w24 + i);
    f4 v0 = ldw(w04 + i + 64), v1 = ldw(w14 + i + 64), v2 = ldw(w24 + i + 64);
    s0 += dot4(u0, av); s1 += dot4(u1, av); s2 += dot4(u2, av);
    s3 += dot4(u0, bv); s4 += dot4(u1, bv); s5 += dot4(u2, bv);
    t0 += dot4(v0, av2); t1 += dot4(v1, av2); t2 += dot4(v2, av2);
    t3 += dot4(v0, bv2); t4 += dot4(v1, bv2); t5 += dot4(v2, bv2);
  }
  for (; i < n4; i += 64) {
    f4 av = a4[i], bv = b4[i];
    f4 u0 = ldw(w04 + i), u1 = ldw(w14 + i), u2 = ldw(w24 + i);
    s0 += dot4(u0, av); s1 += dot4(u1, av); s2 += dot4(u2, av);
    s3 += dot4(u0, bv); s4 += dot4(u1, bv); s5 += dot4(u2, bv);
  }
  for (int t = p + (n4 << 2) + lane; t < L; t += 64) {
    float w0 = w0r[t], w1 = w1r[t], w2 = w2r[t];
    float av = xa0[t], bv = xb0[t];
    s0 += w0 * av; s1 += w1 * av; s2 += w2 * av;
    s3 += w0 * bv; s4 += w1 * bv; s5 += w2 * bv;
  }
  r0 = s0 + t0; r1 = s1 + t1; r2 = s2 + t2;
  r3 = s3 + t3; r4 = s4 + t4; r5 = s5 + t5;
}

// hh (aligned rows, L%4==0), single x.
__device__ __forceinline__ void dot3_a(const float* __restrict__ w0r,
                                       const float* __restrict__ w1r,
                                       const float* __restrict__ w2r,
                                       int L, const float* __restrict__ x,
                                       float& r0, float& r1, float& r2) {
  const int lane = threadIdx.x & 63;
  const int n4 = L >> 2;
  const f4* __restrict__ w04 = (const f4*)w0r;
  const f4* __restrict__ w14 = (const f4*)w1r;
  const f4* __restrict__ w24 = (const f4*)w2r;
  const f4* __restrict__ x4  = (const f4*)x;
  float a0 = 0.f, a1 = 0.f, a2 = 0.f, b0 = 0.f, b1 = 0.f, b2 = 0.f;
  int i = lane;
  for (; i + 64 < n4; i += 128) {
    f4 xa = x4[i], xb = x4[i + 64];
    f4 u0 = ldw(w04 + i),      u1 = ldw(w14 + i),      u2 = ldw(w24 + i);
    f4 v0 = ldw(w04 + i + 64), v1 = ldw(w14 + i + 64), v2 = ldw(w24 + i + 64);
    a0 += dot4(u0, xa); a1 += dot4(u1, xa); a2 += dot4(u2, xa);
    b0 += dot4(v0, xb); b1 += dot4(v1, xb); b2 += dot4(v2, xb);
  }
  for (; i < n4; i += 64) {
    f4 xa = x4[i];
    a0 += dot4(ldw(w04 + i), xa);
    a1 += dot4(ldw(w14 + i), xa);
    a2 += dot4(ldw(w24 + i), xa);
  }
  r0 = a0 + b0; r1 = a1 + b1; r2 = a2 + b2;
}

// hh dual-x (aligned, L%4==0).
__device__ __forceinline__ void dot3_a2(const float* __restrict__ w0r,
                                        const float* __restrict__ w1r,
                                        const float* __restrict__ w2r,
                                        int L, const float* __restrict__ xa,
                                        const float* __restrict__ xb,
                                        float& r0, float& r1, float& r2,
                                        float& r3, float& r4, float& r5) {
  const int lane = threadIdx.x & 63;
  const int n4 = L >> 2;
  const f4* __restrict__ w04 = (const f4*)w0r;
  const f4* __restrict__ w14 = (const f4*)w1r;
  const f4* __restrict__ w24 = (const f4*)w2r;
  const f4* __restrict__ a4  = (const f4*)xa;
  const f4* __restrict__ b4  = (const f4*)xb;
  float s0 = 0.f, s1 = 0.f, s2 = 0.f, s3 = 0.f, s4 = 0.f, s5 = 0.f;
  float t0 = 0.f, t1 = 0.f, t2 = 0.f, t3 = 0.f, t4 = 0.f, t5 = 0.f;
  int i = lane;
  for (; i + 64 < n4; i += 128) {
    f4 av = a4[i], bv = b4[i], av2 = a4[i + 64], bv2 = b4[i + 64];
    f4 u0 = ldw(w04 + i),      u1 = ldw(w14 + i),      u2 = ldw(w24 + i);
    f4 v0 = ldw(w04 + i + 64), v1 = ldw(w14 + i + 64), v2 = ldw(w24 + i + 64);
    s0 += dot4(u0, av); s1 += dot4(u1, av); s2 += dot4(u2, av);
    s3 += dot4(u0, bv); s4 += dot4(u1, bv); s5 += dot4(u2, bv);
    t0 += dot4(v0, av2); t1 += dot4(v1, av2); t2 += dot4(v2, av2);
    t3 += dot4(v0, bv2); t4 += dot4(v1, bv2); t5 += dot4(v2, bv2);
  }
  for (; i < n4; i += 64) {
    f4 av = a4[i], bv = b4[i];
    f4 u0 = ldw(w04 + i), u1 = ldw(w14 + i), u2 = ldw(w24 + i);
    s0 += dot4(u0, av); s1 += dot4(u1, av); s2 += dot4(u2, av);
    s3 += dot4(u0, bv); s4 += dot4(u1, bv); s5 += dot4(u2, bv);
  }
  r0 = s0 + t0; r1 = s1 + t1; r2 = s2 + t2;
  r3 = s3 + t3; r4 = s4 + t4; r5 = s5 + t5;
}

// Single-row aligned dot (used by k_out).
__device__ __forceinline__ float dota(const float* __restrict__ wr, int L,
                                      const float* __restrict__ x) {
  const int lane = threadIdx.x & 63;
  const int n4 = L >> 2;
  const f4* __restrict__ w4 = (const f4*)wr;
  const f4* __restrict__ x4 = (const f4*)x;
  float a = 0.f, b = 0.f;
  int i = lane;
  for (; i + 64 < n4; i += 128) {
    a += dot4(ldw(w4 + i), x4[i]);
    b += dot4(ldw(w4 + i + 64), x4[i + 64]);
  }
  for (; i < n4; i += 64) a += dot4(ldw(w4 + i), x4[i]);
  return wave_sum(a + b);
}

// ---------------- Kernel A: build shifted cat copies ------------------------
__global__ __launch_bounds__(256) void k_concat(
    const float* __restrict__ x,
    const float* __restrict__ h1_s, const float* __restrict__ h2_s,
    const float* __restrict__ k1_s, const float* __restrict__ k2_s,
    const float* __restrict__ f1_s, const float* __restrict__ f2_s,
    float* __restrict__ ws) {
  int t = blockIdx.x * blockDim.x + threadIdx.x;
  if (t < OSC) {
    float h1 = h1_s[t], h2 = h2_s[t];
    float f1 = f1_s[t], f2 = f2_s[t];
    float k1 = k1_s[t], k2 = k2_s[t];
    put4(ws, WS_M_SH, 5 + t, h1);
    put4(ws, WS_M_SH, 5 + OSC + t, h2);
    put4(ws, WS_K1_SH, 1 + t, h1);
    put4(ws, WS_K1_SH, 1 + OSC + t, f1);
    put4(ws, WS_K2_SH, 1 + t, h2);
    put4(ws, WS_K2_SH, 1 + OSC + t, f2);
    put4(ws, WS_F1_SH, 1 + t, f1);
    put4(ws, WS_F2_SH, 1 + t, f2);
    put4(ws, WS_H1_SH, 1 + OSC + t, k1);
    put4(ws, WS_H2_SH, 1 + OSC + t, k2);
  }
  if (t == 0) {
    put4(ws, WS_M_SH, 0, x[0]);
    put4(ws, WS_M_SH, 1, x[1]);
    put4(ws, WS_M_SH, 2, x[8]);
    put4(ws, WS_M_SH, 3, x[9]);
    put4(ws, WS_M_SH, 4, x[10]);
    put4(ws, WS_K1_SH, 0, x[3]);
    put4(ws, WS_K2_SH, 0, x[6]);
    put4(ws, WS_F1_SH, 0, x[4]);
    put4(ws, WS_F2_SH, 0, x[7]);
    put4(ws, WS_H1_SH, 0, x[2]);
    put4(ws, WS_H2_SH, 0, x[5]);
  }
}

// ---------------- Kernel B: m + k + f GRUs, block-per-row, 2 waves ----------
// Wave 0: all 3 ih gates (3 w streams + shared x). Wave 1: all 3 hh gates.
// blocks [0,4096): m row; [4096,6144): k row (dual); [6144,8192): f row (dual).
__global__ __launch_bounds__(128) void k_phase1(
    const float* __restrict__ m_w_ih, const float* __restrict__ m_w_hh,
    const float* __restrict__ m_b_ih, const float* __restrict__ m_b_hh,
    const float* __restrict__ m_s,
    const float* __restrict__ k_w_ih, const float* __restrict__ k_w_hh,
    const float* __restrict__ k_b_ih, const float* __restrict__ k_b_hh,
    const float* __restrict__ k1_s, const float* __restrict__ k2_s,
    const float* __restrict__ f_w_ih, const float* __restrict__ f_w_hh,
    const float* __restrict__ f_b_ih, const float* __restrict__ f_b_hh,
    const float* __restrict__ f1_s, const float* __restrict__ f2_s,
    float* __restrict__ ws) {
  __shared__ float red[12];
  const int wave = threadIdx.x >> 6;
  const int lane = threadIdx.x & 63;
  const int blk = blockIdx.x;

  if (blk < MHID) {  // ---- m GRU
    const int j = blk;
    float v0, v1, v2;
    if (wave == 0) {
      const float* w0 = m_w_ih + (size_t)j * 4101;
      dot3_ih(w0, w0 + (size_t)MHID * 4101, w0 + (size_t)2 * MHID * 4101,
              4101, ws, WS_M_SH, v0, v1, v2);
    } else {
      const float* w0 = m_w_hh + (size_t)j * MHID;
      dot3_a(w0, w0 + (size_t)MHID * MHID, w0 + (size_t)2 * MHID * MHID,
             MHID, m_s, v0, v1, v2);
    }
    wsum3(v0, v1, v2);
    if (lane == 0) { red[wave * 3 + 0] = v0; red[wave * 3 + 1] = v1; red[wave * 3 + 2] = v2; }
    __syncthreads();
    if (threadIdx.x == 0) {
      float r = sigf(red[0] + m_b_ih[j] + red[3] + m_b_hh[j]);
      float z = sigf(red[1] + m_b_ih[j + MHID] + red[4] + m_b_hh[j + MHID]);
      float n = tanhf(red[2] + m_b_ih[j + 2 * MHID] + r * (red[5] + m_b_hh[j + 2 * MHID]));
      ws[WS_M_NEW + j] = (1.f - z) * n + z * m_s[j];
    }
  } else if (blk < MHID + OSC) {  // ---- k GRUs (dual)
    const int j = blk - MHID;
    float v0, v1, v2, v3, v4, v5;
    if (wave == 0) {
      const float* w0 = k_w_ih + (size_t)j * 4097;
      dot3_ih2(w0, w0 + (size_t)OSC * 4097, w0 + (size_t)2 * OSC * 4097,
               4097, ws, WS_K1_SH, WS_K2_SH, v0, v1, v2, v3, v4, v5);
    } else {
      const float* w0 = k_w_hh + (size_t)j * OSC;
      dot3_a2(w0, w0 + (size_t)OSC * OSC, w0 + (size_t)2 * OSC * OSC,
              OSC, k1_s, k2_s, v0, v1, v2, v3, v4, v5);
    }
    wsum6(v0, v1, v2, v3, v4, v5);
    if (lane == 0) {
      int b = wave * 6;
      red[b + 0] = v0; red[b + 1] = v1; red[b + 2] = v2;
      red[b + 3] = v3; red[b + 4] = v4; red[b + 5] = v5;
    }
    __syncthreads();
    if (threadIdx.x == 0) {
      float bi1 = k_b_ih[j], bi2 = k_b_ih[j + OSC], bi3 = k_b_ih[j + 2 * OSC];
      float bh1 = k_b_hh[j], bh2 = k_b_hh[j + OSC], bh3 = k_b_hh[j + 2 * OSC];
      float r1 = sigf(red[0] + bi1 + red[6] + bh1);
      float z1 = sigf(red[1] + bi2 + red[7] + bh2);
      float n1 = tanhf(red[2] + bi3 + r1 * (red[8] + bh3));
      ws[WS_K1_NEW + j] = (1.f - z1) * n1 + z1 * k1_s[j];
      float r2 = sigf(red[3] + bi1 + red[9] + bh1);
      float z2 = sigf(red[4] + bi2 + red[10] + bh2);
      float n2 = tanhf(red[5] + bi3 + r2 * (red[11] + bh3));
      ws[WS_K2_NEW + j] = (1.f - z2) * n2 + z2 * k2_s[j];
    }
  } else {  // ---- f GRUs (dual), ih rows len 2049
    const int j = blk - MHID - OSC;
    float v0, v1, v2, v3, v4, v5;
    if (wave == 0) {
      const float* w0 = f_w_ih + (size_t)j * 2049;
      dot3_ih2(w0, w0 + (size_t)OSC * 2049, w0 + (size_t)2 * OSC * 2049,
               2049, ws, WS_F1_SH, WS_F2_SH, v0, v1, v2, v3, v4, v5);
    } else {
      const float* w0 = f_w_hh + (size_t)j * OSC;
      dot3_a2(w0, w0 + (size_t)OSC * OSC, w0 + (size_t)2 * OSC * OSC,
              OSC, f1_s, f2_s, v0, v1, v2, v3, v4, v5);
    }
    wsum6(v0, v1, v2, v3, v4, v5);
    if (lane == 0) {
      int b = wave * 6;
      red[b + 0] = v0; red[b + 1] = v1; red[b + 2] = v2;
      red[b + 3] = v3; red[b + 4] = v4; red[b + 5] = v5;
    }
    __syncthreads();
    if (threadIdx.x == 0) {
      float bi1 = f_b_ih[j], bi2 = f_b_ih[j + OSC], bi3 = f_b_ih[j + 2 * OSC];
      float bh1 = f_b_hh[j], bh2 = f_b_hh[j + OSC], bh3 = f_b_hh[j + 2 * OSC];
      float r1 = sigf(red[0] + bi1 + red[6] + bh1);
      float z1 = sigf(red[1] + bi2 + red[7] + bh2);
      float n1 = tanhf(red[2] + bi3 + r1 * (red[8] + bh3));
      ws[WS_F1_NEW + j] = (1.f - z1) * n1 + z1 * f1_s[j];
      float r2 = sigf(red[3] + bi1 + red[9] + bh1);
      float z2 = sigf(red[4] + bi2 + red[10] + bh2);
      float n2 = tanhf(red[5] + bi3 + r2 * (red[11] + bh3));
      ws[WS_F2_NEW + j] = (1.f - z2) * n2 + z2 * f2_s[j];
    }
  }
}

// ---------------- Kernel C: out_m, 4 rows per wave --------------------------
__global__ __launch_bounds__(256) void k_mout(const float* __restrict__ m_out_w,
                                              const float* __restrict__ m_out_b,
                                              float* __restrict__ ws) {
  const int wave = threadIdx.x >> 6;
  const int lane = threadIdx.x & 63;
  const int c0 = (blockIdx.x * 4 + wave) * 4;  // rows c0..c0+3 of 4096
  const float* __restrict__ x = ws + WS_M_NEW;
  const f4* __restrict__ x4 = (const f4*)x;
  const f4* __restrict__ w04 = (const f4*)(m_out_w + (size_t)(c0 + 0) * MHID);
  const f4* __restrict__ w14 = (const f4*)(m_out_w + (size_t)(c0 + 1) * MHID);
  const f4* __restrict__ w24 = (const f4*)(m_out_w + (size_t)(c0 + 2) * MHID);
  const f4* __restrict__ w34 = (const f4*)(m_out_w + (size_t)(c0 + 3) * MHID);
  const int n4 = MHID >> 2;
  float s0 = 0.f, s1 = 0.f, s2 = 0.f, s3 = 0.f;
  float t0 = 0.f, t1 = 0.f, t2 = 0.f, t3 = 0.f;
  int i = lane;
  for (; i + 64 < n4; i += 128) {
    f4 xa = x4[i], xb = x4[i + 64];
    f4 u0 = ldw(w04 + i),      u1 = ldw(w14 + i),      u2 = ldw(w24 + i),      u3 = ldw(w34 + i);
    f4 v0 = ldw(w04 + i + 64), v1 = ldw(w14 + i + 64), v2 = ldw(w24 + i + 64), v3 = ldw(w34 + i + 64);
    s0 += dot4(u0, xa); s1 += dot4(u1, xa); s2 += dot4(u2, xa); s3 += dot4(u3, xa);
    t0 += dot4(v0, xb); t1 += dot4(v1, xb); t2 += dot4(v2, xb); t3 += dot4(v3, xb);
  }
  for (; i < n4; i += 64) {
    f4 xa = x4[i];
    s0 += dot4(ldw(w04 + i), xa); s1 += dot4(ldw(w14 + i), xa);
    s2 += dot4(ldw(w24 + i), xa); s3 += dot4(ldw(w34 + i), xa);
  }
  s0 += t0; s1 += t1; s2 += t2; s3 += t3;
  wsum4(s0, s1, s2, s3);
  if (lane == 0) {
    float vv[4] = {s0, s1, s2, s3};
#pragma unroll
    for (int r = 0; r < 4; ++r) {
      int c = c0 + r;
      float v = vv[r] + m_out_b[c];
      const int base = (c < OSC) ? WS_H1_SH : WS_H2_SH;
      put4(ws, base, 1 + (c & (OSC - 1)), v);
    }
  }
}

// ---------------- Kernel D: h GRUs, block-per-row, 2 waves (dual) -----------
__global__ __launch_bounds__(128) void k_hgru(
    const float* __restrict__ h_w_ih, const float* __restrict__ h_w_hh,
    const float* __restrict__ h_b_ih, const float* __restrict__ h_b_hh,
    const float* __restrict__ h1_s, const float* __restrict__ h2_s,
    float* __restrict__ ws) {
  __shared__ float red[12];
  const int wave = threadIdx.x >> 6;
  const int lane = threadIdx.x & 63;
  const int j = blockIdx.x;
  float v0, v1, v2, v3, v4, v5;
  if (wave == 0) {
    const float* w0 = h_w_ih + (size_t)j * 4097;
    dot3_ih2(w0, w0 + (size_t)OSC * 4097, w0 + (size_t)2 * OSC * 4097,
             4097, ws, WS_H1_SH, WS_H2_SH, v0, v1, v2, v3, v4, v5);
  } else {
    const float* w0 = h_w_hh + (size_t)j * OSC;
    dot3_a2(w0, w0 + (size_t)OSC * OSC, w0 + (size_t)2 * OSC * OSC,
            OSC, h1_s, h2_s, v0, v1, v2, v3, v4, v5);
  }
  wsum6(v0, v1, v2, v3, v4, v5);
  if (lane == 0) {
    int b = wave * 6;
    red[b + 0] = v0; red[b + 1] = v1; red[b + 2] = v2;
    red[b + 3] = v3; red[b + 4] = v4; red[b + 5] = v5;
  }
  __syncthreads();
  if (threadIdx.x == 0) {
    float bi1 = h_b_ih[j], bi2 = h_b_ih[j + OSC], bi3 = h_b_ih[j + 2 * OSC];
    float bh1 = h_b_hh[j], bh2 = h_b_hh[j + OSC], bh3 = h_b_hh[j + 2 * OSC];
    float r1 = sigf(red[0] + bi1 + red[6] + bh1);
    float z1 = sigf(red[1] + bi2 + red[7] + bh2);
    float n1 = tanhf(red[2] + bi3 + r1 * (red[8] + bh3));
    ws[WS_H1_NEW + j] = (1.f - z1) * n1 + z1 * h1_s[j];
    float r2 = sigf(red[3] + bi1 + red[9] + bh1);
    float z2 = sigf(red[4] + bi2 + red[10] + bh2);
    float n2 = tanhf(red[5] + bi3 + r2 * (red[11] + bh3));
    ws[WS_H2_NEW + j] = (1.f - z2) * n2 + z2 * h2_s[j];
  }
}

// ---------------- Kernel E: six output projections --------------------------
__global__ __launch_bounds__(64) void k_out(
    const float* __restrict__ h_out_w, const float* __restrict__ h_out_b,
    const float* __restrict__ k_out_w, const float* __restrict__ k_out_b,
    const float* __restrict__ f_out_w, const float* __restrict__ f_out_b,
    const float* __restrict__ ws, float* __restrict__ out) {
  const int b = blockIdx.x;
  const int lane = threadIdx.x & 63;
  const float* w;
  const float* v;
  float bias;
  switch (b) {
    case 0:  w = h_out_w; v = ws + WS_H1_NEW; bias = h_out_b[0]; break;
    case 1:  w = k_out_w; v = ws + WS_K1_NEW; bias = k_out_b[0]; break;
    case 2:  w = f_out_w; v = ws + WS_F1_NEW; bias = f_out_b[0]; break;
    case 3:  w = h_out_w; v = ws + WS_H2_NEW; bias = h_out_b[0]; break;
    case 4:  w = k_out_w; v = ws + WS_K2_NEW; bias = k_out_b[0]; break;
    default: w = f_out_w; v = ws + WS_F2_NEW; bias = f_out_b[0]; break;
  }
  float s = dota(w, OSC, v);
  if (lane == 0) out[b] = s + bias;
}

extern "C" void kernel_launch(void* const* d_in, const int* in_sizes, int n_in,
                              void* d_out, int out_size, void* d_ws, size_t ws_size,
                              hipStream_t stream) {
  const float* x      = (const float*)d_in[0];
  const float* m_s    = (const float*)d_in[1];
  const float* h1_s   = (const float*)d_in[2];
  const float* h2_s   = (const float*)d_in[3];
  const float* k1_s   = (const float*)d_in[4];
  const float* k2_s   = (const float*)d_in[5];
  const float* f1_s   = (const float*)d_in[6];
  const float* f2_s   = (const float*)d_in[7];
  const float* m_w_ih = (const float*)d_in[8];
  const float* m_w_hh = (const float*)d_in[9];
  const float* m_b_ih = (const float*)d_in[10];
  const float* m_b_hh = (const float*)d_in[11];
  const float* m_out_w = (const float*)d_in[12];
  const float* m_out_b = (const float*)d_in[13];
  const float* h_w_ih = (const float*)d_in[14];
  const float* h_w_hh = (const float*)d_in[15];
  const float* h_b_ih = (const float*)d_in[16];
  const float* h_b_hh = (const float*)d_in[17];
  const float* h_out_w = (const float*)d_in[18];
  const float* h_out_b = (const float*)d_in[19];
  const float* k_w_ih = (const float*)d_in[20];
  const float* k_w_hh = (const float*)d_in[21];
  const float* k_b_ih = (const float*)d_in[22];
  const float* k_b_hh = (const float*)d_in[23];
  const float* k_out_w = (const float*)d_in[24];
  const float* k_out_b = (const float*)d_in[25];
  const float* f_w_ih = (const float*)d_in[26];
  const float* f_w_hh = (const float*)d_in[27];
  const float* f_b_ih = (const float*)d_in[28];
  const float* f_b_hh = (const float*)d_in[29];
  const float* f_out_w = (const float*)d_in[30];
  const float* f_out_b = (const float*)d_in[31];

  float* ws  = (float*)d_ws;
  float* out = (float*)d_out;

  k_concat<<<8, 256, 0, stream>>>(x, h1_s, h2_s, k1_s, k2_s, f1_s, f2_s, ws);
  k_phase1<<<MHID + 2 * OSC, 128, 0, stream>>>(
      m_w_ih, m_w_hh, m_b_ih, m_b_hh, m_s,
      k_w_ih, k_w_hh, k_b_ih, k_b_hh, k1_s, k2_s,
      f_w_ih, f_w_hh, f_b_ih, f_b_hh, f1_s, f2_s, ws);
  k_mout<<<256, 256, 0, stream>>>(m_out_w, m_out_b, ws);
  k_hgru<<<OSC, 128, 0, stream>>>(h_w_ih, h_w_hh, h_b_ih, h_b_hh, h1_s, h2_s, ws);
  k_out<<<6, 64, 0, stream>>>(h_out_w, h_out_b, k_out_w, k_out_b, f_out_w, f_out_b, ws, out);
}